// Round 11
// baseline (1714.853 us; speedup 1.0000x reference)
//
#include <hip/hip_runtime.h>

// Problem constants
constexpr int N_TOK = 8192;      // B*S
constexpr int D_IN  = 2048;
constexpr int H_OUT = 4096;
constexpr int NEXP  = 8;
constexpr float ENT_W = 0.1f;
constexpr float MAX_USAGE = 0.3f;

// GEMM tiling: 128x128 tile, BK=32, dbuf -> LDS exactly 32 KB -> 5 blocks/CU
constexpr int TM = 128;               // token-tile
constexpr int TH = 128;               // H-tile
constexpr int BK = 32;                // K-step (64 bytes bf16 per row)
constexpr int NKT = D_IN / BK;        // 64 K-tiles
constexpr int TILES_H = H_OUT / TH;   // 32
constexpr int TM_MAX  = N_TOK / TM;   // 64 worst-case token tiles per expert
constexpr int REGION  = 8192;         // per-expert list capacity
constexpr int BUFSZ   = TM * BK;      // shorts per LDS slot (4096 = 8 KB)

typedef __attribute__((ext_vector_type(8))) short bf16x8;
typedef __attribute__((ext_vector_type(4))) float f32x4;

__device__ __forceinline__ short f2bf(float f) {
    unsigned u = __float_as_uint(f);
    u += 0x7FFF + ((u >> 16) & 1);   // RNE
    return (short)(u >> 16);
}

__device__ __forceinline__ void gload16(const void* g, void* l) {
    __builtin_amdgcn_global_load_lds(
        (const __attribute__((address_space(1))) unsigned int*)g,
        (__attribute__((address_space(3))) unsigned int*)l, 16, 0, 0);
}

// ---------------------------------------------------------------------------
// Kernel 1: gating (one wave per token, fuses x->bf16) + grid-stride
// expert_w -> bf16 conversion appended (one launch, same total bytes).
// ---------------------------------------------------------------------------
__global__ __launch_bounds__(256) void gate_cvt_kernel(
    const float* __restrict__ x, const float* __restrict__ gate_w,
    const float* __restrict__ gate_b, int* __restrict__ topk_idx,
    float* __restrict__ topk_w, float* __restrict__ ent_partial,
    short* __restrict__ xb,
    const float* __restrict__ expert_w, short* __restrict__ wb)
{
    __shared__ float ent_s[4];
    const int wv = threadIdx.x >> 6;
    const int lane = threadIdx.x & 63;
    const int t = blockIdx.x * 4 + wv;

    float acc[NEXP];
#pragma unroll
    for (int e = 0; e < NEXP; ++e) acc[e] = 0.f;

    const float4* xr = (const float4*)(x + (size_t)t * D_IN);
    short* xbr = xb + (size_t)t * D_IN;
#pragma unroll
    for (int i = 0; i < D_IN / 256; ++i) {           // 8 iters
        float4 xv = xr[lane + i * 64];
        short4 s4;
        s4.x = f2bf(xv.x); s4.y = f2bf(xv.y); s4.z = f2bf(xv.z); s4.w = f2bf(xv.w);
        *(short4*)(xbr + i * 256 + lane * 4) = s4;
#pragma unroll
        for (int e = 0; e < NEXP; ++e) {
            float4 gv = ((const float4*)(gate_w + e * D_IN))[lane + i * 64];
            acc[e] += xv.x * gv.x + xv.y * gv.y + xv.z * gv.z + xv.w * gv.w;
        }
    }
#pragma unroll
    for (int e = 0; e < NEXP; ++e)
#pragma unroll
        for (int m = 32; m >= 1; m >>= 1) acc[e] += __shfl_xor(acc[e], m, 64);

    if (lane == 0) {
        float lg[NEXP], p[NEXP];
        float mx = -1e30f;
#pragma unroll
        for (int e = 0; e < NEXP; ++e) { lg[e] = acc[e] + gate_b[e]; mx = fmaxf(mx, lg[e]); }
        float s = 0.f;
#pragma unroll
        for (int e = 0; e < NEXP; ++e) { p[e] = expf(lg[e] - mx); s += p[e]; }
        float inv = 1.f / s;
        float ent = 0.f;
#pragma unroll
        for (int e = 0; e < NEXP; ++e) { p[e] *= inv; ent -= p[e] * logf(p[e] + 1e-10f); }
        int e1 = 0; float b1 = p[0];
#pragma unroll
        for (int e = 1; e < NEXP; ++e) if (p[e] > b1) { b1 = p[e]; e1 = e; }
        int e2 = (e1 == 0) ? 1 : 0; float b2 = p[e2];
#pragma unroll
        for (int e = 0; e < NEXP; ++e)
            if (e != e1 && e != ((e1 == 0) ? 1 : 0) && p[e] > b2) { b2 = p[e]; e2 = e; }
        topk_idx[2 * t]     = e1;  topk_idx[2 * t + 1] = e2;
        topk_w[2 * t]       = b1;  topk_w[2 * t + 1]   = b2;
        ent_s[wv] = ent;
    }
    __syncthreads();
    if (threadIdx.x == 0)
        ent_partial[blockIdx.x] = ent_s[0] + ent_s[1] + ent_s[2] + ent_s[3];

    // ---- appended: expert_w fp32 -> bf16 (grid-stride, 16 iters) ----
    const int n8 = (NEXP * H_OUT * D_IN) / 8;        // 8.39M chunks
    int stride = gridDim.x * 256;
    for (int i = blockIdx.x * 256 + threadIdx.x; i < n8; i += stride) {
        const float4* p = (const float4*)expert_w + (size_t)i * 2;
        float4 a = p[0], b = p[1];
        bf16x8 v;
        v[0] = f2bf(a.x); v[1] = f2bf(a.y); v[2] = f2bf(a.z); v[3] = f2bf(a.w);
        v[4] = f2bf(b.x); v[5] = f2bf(b.y); v[6] = f2bf(b.z); v[7] = f2bf(b.w);
        *(bf16x8*)(wb + (size_t)i * 8) = v;
    }
}

// ---------------------------------------------------------------------------
// Kernel 2: scatter. LDS-binned, fixed per-expert regions.
// ---------------------------------------------------------------------------
__global__ __launch_bounds__(256) void scatter_kernel(
    const int* __restrict__ topk_idx, const float* __restrict__ topk_w,
    int* __restrict__ cursors, int* __restrict__ tok_list,
    float* __restrict__ w_list)
{
    __shared__ int lcnt[NEXP], lbase[NEXP];
    const int tid = threadIdx.x;
    const int t = blockIdx.x * 256 + tid;
    if (tid < NEXP) lcnt[tid] = 0;
    __syncthreads();
    int e0 = topk_idx[2 * t], e1 = topk_idx[2 * t + 1];
    float w0 = topk_w[2 * t], w1 = topk_w[2 * t + 1];
    int p0 = atomicAdd(&lcnt[e0], 1);
    int p1 = atomicAdd(&lcnt[e1], 1);
    __syncthreads();
    if (tid < NEXP) lbase[tid] = atomicAdd(&cursors[tid], lcnt[tid]);
    __syncthreads();
    int d0 = e0 * REGION + lbase[e0] + p0;
    int d1 = e1 * REGION + lbase[e1] + p1;
    tok_list[d0] = t;  w_list[d0] = w0;
    tok_list[d1] = t;  w_list[d1] = w1;
}

// ---------------------------------------------------------------------------
// Kernel 3: finalize — entropy reduce + overuse penalty (counts = cursors).
// Launched AFTER moe_gemm (off the critical path; gemm needs only scatter).
// ---------------------------------------------------------------------------
__global__ __launch_bounds__(256) void finalize_kernel(
    const int* __restrict__ counts, const float* __restrict__ ent_partial,
    float* __restrict__ loss_out)
{
    __shared__ float red[256];
    float s = 0.f;
    for (int i = threadIdx.x; i < N_TOK / 4; i += 256) s += ent_partial[i];
    red[threadIdx.x] = s;
    __syncthreads();
    for (int st = 128; st > 0; st >>= 1) {
        if (threadIdx.x < st) red[threadIdx.x] += red[threadIdx.x + st];
        __syncthreads();
    }
    if (threadIdx.x == 0) {
        float loss = ENT_W * red[0] / (float)N_TOK;
        for (int e = 0; e < NEXP; ++e) {
            float r = (float)counts[e] / (float)N_TOK - MAX_USAGE;
            if (r > 0.f) loss += r;
        }
        loss_out[0] = loss;
    }
}

// ---------------------------------------------------------------------------
// Kernel 4: grouped GEMM — r8's proven 128x128/BK=32 depth-2 counted pipeline
// (2 barriers/tile, 4 gloads + 8 ds_read + 16 MFMA + vmcnt(4)), with the
// token/weight lists read DIRECTLY from global (L2-hot) instead of LDS:
// LDS = exactly 32 KB -> 5 blocks/CU (20 waves; was 4 blocks @ 33 KB).
// Swizzle: source slot (l&3)^((l>>3)&3), linear LDS dest, frag read slot
// kg^((row>>1)&3) — involution, 0 conflicts (measured r8).
// ---------------------------------------------------------------------------
__global__ __launch_bounds__(256, 5) void moe_gemm(
    const short* __restrict__ xb, const short* __restrict__ wb,
    const float* __restrict__ expert_b, const int* __restrict__ tok_list,
    const float* __restrict__ w_list, const int* __restrict__ counts,
    float* __restrict__ out)
{
    const int bid = blockIdx.x;
    const int e   = bid / (TM_MAX * TILES_H);
    const int rem = bid % (TM_MAX * TILES_H);
    const int tm  = rem / TILES_H;
    const int th  = rem % TILES_H;     // th inner: consecutive bids share A-tile

    const int cnt = counts[e];
    if (tm * TM >= cnt) return;
    const int valid = cnt - tm * TM;
    const int base  = e * REGION + tm * TM;
    const int hbase = th * TH;

    __shared__ __align__(16) short A_s[2][BUFSZ];   // 2 x 8 KB
    __shared__ __align__(16) short B_s[2][BUFSZ];   // 2 x 8 KB  (total 32768 B)

    const int tid = threadIdx.x;
    const int lane = tid & 63;
    const int wv = tid >> 6;

    // staging: 8 x 1KB chunks per operand-tile; wave wv owns chunks wv*2+j.
    // chunk c covers rows c*16..c*16+15; lane l -> row c*16+(l>>2),
    // source slot (l&3)^((l>>3)&3) (involution). Token ids read direct.
    const char* asrc[2];
    const char* bsrc[2];
    int dst_off[2];                    // shorts, wave-uniform (+lane*16B by HW)
#pragma unroll
    for (int j = 0; j < 2; ++j) {
        int c = wv * 2 + j;
        int r = c * 16 + (lane >> 2);
        int s2 = (lane & 3) ^ ((lane >> 3) & 3);
        int tok = (r < valid) ? tok_list[base + r] : tok_list[base];
        asrc[j] = (const char*)(xb + (size_t)tok * D_IN) + s2 * 16;
        bsrc[j] = (const char*)(wb + ((size_t)e * H_OUT + hbase + r) * D_IN) + s2 * 16;
        dst_off[j] = c * 512;
    }

    const int rr = lane & 15, kg = lane >> 4;
    const int wr = wv >> 1, wc = wv & 1;

    // fragment LDS offsets (shorts), swizzled to match staging involution
    int aoff[4], boff[4];
#pragma unroll
    for (int mi = 0; mi < 4; ++mi) {
        int row = wr * 64 + mi * 16 + rr;
        aoff[mi] = row * 32 + (kg ^ ((row >> 1) & 3)) * 8;
        int rowb = wc * 64 + mi * 16 + rr;
        boff[mi] = rowb * 32 + (kg ^ ((rowb >> 1) & 3)) * 8;
    }

    f32x4 acc[4][4] = {};

#define STAGE_KT(buf)                                                      \
    {                                                                      \
        short* Aso = (short*)A_s[buf];                                     \
        short* Bso = (short*)B_s[buf];                                     \
        gload16(asrc[0], Aso + dst_off[0]); asrc[0] += BK * 2;             \
        gload16(bsrc[0], Bso + dst_off[0]); bsrc[0] += BK * 2;             \
        gload16(asrc[1], Aso + dst_off[1]); asrc[1] += BK * 2;             \
        gload16(bsrc[1], Bso + dst_off[1]); bsrc[1] += BK * 2;             \
    }

    // prologue: stage K-tiles 0 (buf0) and 1 (buf1); certify tile 0 only.
    STAGE_KT(0);
    STAGE_KT(1);
    asm volatile("s_waitcnt vmcnt(4)" ::: "memory");   // tile 0 landed
    __builtin_amdgcn_sched_barrier(0);
    __builtin_amdgcn_s_barrier();

    for (int kt = 0; kt < NKT; ++kt) {
        const short* Ac = A_s[kt & 1];
        const short* Bc = B_s[kt & 1];

        // consume current tile entirely into registers
        bf16x8 af[4], bv[4];
#pragma unroll
        for (int mi = 0; mi < 4; ++mi) af[mi] = *(const bf16x8*)&Ac[aoff[mi]];
#pragma unroll
        for (int ni = 0; ni < 4; ++ni) bv[ni] = *(const bf16x8*)&Bc[boff[ni]];
        asm volatile("s_waitcnt lgkmcnt(0)" ::: "memory");
        __builtin_amdgcn_sched_barrier(0);
        __builtin_amdgcn_s_barrier();          // all waves done reading buf[kt&1]

        // stage tile kt+2 into the freed buffer (loads fly under MFMA)
        if (kt + 2 < NKT) STAGE_KT(kt & 1);

        __builtin_amdgcn_s_setprio(1);
#pragma unroll
        for (int mi = 0; mi < 4; ++mi)
#pragma unroll
            for (int ni = 0; ni < 4; ++ni)
                acc[mi][ni] = __builtin_amdgcn_mfma_f32_16x16x32_bf16(
                    af[mi], bv[ni], acc[mi][ni], 0, 0, 0);
        __builtin_amdgcn_s_setprio(0);

        // certify tile kt+1 (issued one full tile ago); deep prefetch stays.
        if (kt + 2 < NKT) {
            asm volatile("s_waitcnt vmcnt(4)" ::: "memory");
        } else if (kt + 1 < NKT) {
            asm volatile("s_waitcnt vmcnt(0)" ::: "memory");
        }
        __builtin_amdgcn_sched_barrier(0);
        __builtin_amdgcn_s_barrier();          // buf[(kt+1)&1] valid for all
    }
#undef STAGE_KT

    // epilogue: C/D layout col=lane&15, row=(lane>>4)*4+i.
    // token/weight read direct from global (L2-hot), hoisted per (mi,i).
    const float* bias = expert_b + (size_t)e * H_OUT + hbase;
    float be[4];
#pragma unroll
    for (int ni = 0; ni < 4; ++ni) be[ni] = bias[wc * 64 + ni * 16 + rr];
#pragma unroll
    for (int mi = 0; mi < 4; ++mi) {
#pragma unroll
        for (int i = 0; i < 4; ++i) {
            int r = wr * 64 + mi * 16 + kg * 4 + i;
            if (r < valid) {
                int tok  = tok_list[base + r];
                float w  = w_list[base + r];
                float* orow = out + (size_t)tok * H_OUT + hbase;
#pragma unroll
                for (int ni = 0; ni < 4; ++ni) {
                    int col = wc * 64 + ni * 16 + rr;
                    atomicAdd(orow + col, w * (acc[mi][ni][i] + be[ni]));
                }
            }
        }
    }
}

// ---------------------------------------------------------------------------
// Workspace layout (<= 162 MB):
//   0        topk_idx    64 KB
//   64K      topk_w      64 KB
//   128K     cursors     64 B
//   128K+256 ent_partial 8 KB
//   160K     tok_list    256 KB  (8 regions x 8192)
//   416K     w_list      256 KB
//   1M       xb  bf16    32 MB
//   34M      wb  bf16    128 MB  (row-major)
// ---------------------------------------------------------------------------
extern "C" void kernel_launch(void* const* d_in, const int* in_sizes, int n_in,
                              void* d_out, int out_size, void* d_ws, size_t ws_size,
                              hipStream_t stream) {
    const float* x        = (const float*)d_in[0];
    const float* gate_w   = (const float*)d_in[1];
    const float* gate_b   = (const float*)d_in[2];
    const float* expert_w = (const float*)d_in[3];
    const float* expert_b = (const float*)d_in[4];
    float* out = (float*)d_out;
    char* ws = (char*)d_ws;

    int*   topk_idx    = (int*)(ws);
    float* topk_w      = (float*)(ws + (64 << 10));
    int*   cursors     = (int*)(ws + (128 << 10));
    float* ent_partial = (float*)(ws + (128 << 10) + 256);
    int*   tok_list    = (int*)(ws + (160 << 10));
    float* w_list      = (float*)(ws + (416 << 10));
    short* xb          = (short*)(ws + (1ull << 20));
    short* wb          = (short*)(ws + (34ull << 20));

    hipMemsetAsync(cursors, 0, 64, stream);
    hipMemsetAsync(d_out, 0, (size_t)out_size * sizeof(float), stream);

    gate_cvt_kernel<<<N_TOK / 4, 256, 0, stream>>>(x, gate_w, gate_b, topk_idx,
                                                   topk_w, ent_partial, xb,
                                                   expert_w, wb);
    scatter_kernel<<<N_TOK / 256, 256, 0, stream>>>(topk_idx, topk_w, cursors,
                                                    tok_list, w_list);
    moe_gemm<<<NEXP * TM_MAX * TILES_H, 256, 0, stream>>>(
        xb, wb, expert_b, tok_list, w_list, cursors, out);
    finalize_kernel<<<1, 256, 0, stream>>>(cursors, ent_partial,
                                           out + (size_t)N_TOK * H_OUT);
}

// Round 12
// 652.180 us; speedup vs baseline: 2.6294x; 2.6294x over previous
//
#include <hip/hip_runtime.h>

// Problem constants
constexpr int N_TOK = 8192;      // B*S
constexpr int D_IN  = 2048;
constexpr int H_OUT = 4096;
constexpr int NEXP  = 8;
constexpr float ENT_W = 0.1f;
constexpr float MAX_USAGE = 0.3f;

// GEMM tiling: 128x128 tile, BK=32 -> 33 KB LDS -> 4 blocks/CU (16 waves/CU)
// NOTE (register roofline): acc[4][4] = 64 AGPR + 64 VGPR = 128 unified regs
// = exactly the 4-waves/SIMD budget (512/4). A 5th block/CU spills (r11).
constexpr int TM = 128;               // token-tile
constexpr int TH = 128;               // H-tile
constexpr int BK = 32;                // K-step (64 bytes bf16 per row)
constexpr int NKT = D_IN / BK;        // 64 K-tiles
constexpr int TILES_H = H_OUT / TH;   // 32
constexpr int TM_MAX  = N_TOK / TM;   // 64 worst-case token tiles per expert
constexpr int REGION  = 8192;         // per-expert list capacity
constexpr int BUFSZ   = TM * BK;      // shorts per LDS buffer (4096 = 8 KB)

typedef __attribute__((ext_vector_type(8))) short bf16x8;
typedef __attribute__((ext_vector_type(4))) float f32x4;

__device__ __forceinline__ short f2bf(float f) {
    unsigned u = __float_as_uint(f);
    u += 0x7FFF + ((u >> 16) & 1);   // RNE
    return (short)(u >> 16);
}

__device__ __forceinline__ void gload16(const void* g, void* l) {
    __builtin_amdgcn_global_load_lds(
        (const __attribute__((address_space(1))) unsigned int*)g,
        (__attribute__((address_space(3))) unsigned int*)l, 16, 0, 0);
}

// ---------------------------------------------------------------------------
// Kernel 1: gating (one wave per token, fuses x->bf16) + grid-stride
// expert_w -> bf16 conversion appended (one launch).
// ---------------------------------------------------------------------------
__global__ __launch_bounds__(256) void gate_cvt_kernel(
    const float* __restrict__ x, const float* __restrict__ gate_w,
    const float* __restrict__ gate_b, int* __restrict__ topk_idx,
    float* __restrict__ topk_w, float* __restrict__ ent_partial,
    short* __restrict__ xb,
    const float* __restrict__ expert_w, short* __restrict__ wb)
{
    __shared__ float ent_s[4];
    const int wv = threadIdx.x >> 6;
    const int lane = threadIdx.x & 63;
    const int t = blockIdx.x * 4 + wv;

    float acc[NEXP];
#pragma unroll
    for (int e = 0; e < NEXP; ++e) acc[e] = 0.f;

    const float4* xr = (const float4*)(x + (size_t)t * D_IN);
    short* xbr = xb + (size_t)t * D_IN;
#pragma unroll
    for (int i = 0; i < D_IN / 256; ++i) {           // 8 iters
        float4 xv = xr[lane + i * 64];
        short4 s4;
        s4.x = f2bf(xv.x); s4.y = f2bf(xv.y); s4.z = f2bf(xv.z); s4.w = f2bf(xv.w);
        *(short4*)(xbr + i * 256 + lane * 4) = s4;
#pragma unroll
        for (int e = 0; e < NEXP; ++e) {
            float4 gv = ((const float4*)(gate_w + e * D_IN))[lane + i * 64];
            acc[e] += xv.x * gv.x + xv.y * gv.y + xv.z * gv.z + xv.w * gv.w;
        }
    }
#pragma unroll
    for (int e = 0; e < NEXP; ++e)
#pragma unroll
        for (int m = 32; m >= 1; m >>= 1) acc[e] += __shfl_xor(acc[e], m, 64);

    if (lane == 0) {
        float lg[NEXP], p[NEXP];
        float mx = -1e30f;
#pragma unroll
        for (int e = 0; e < NEXP; ++e) { lg[e] = acc[e] + gate_b[e]; mx = fmaxf(mx, lg[e]); }
        float s = 0.f;
#pragma unroll
        for (int e = 0; e < NEXP; ++e) { p[e] = expf(lg[e] - mx); s += p[e]; }
        float inv = 1.f / s;
        float ent = 0.f;
#pragma unroll
        for (int e = 0; e < NEXP; ++e) { p[e] *= inv; ent -= p[e] * logf(p[e] + 1e-10f); }
        int e1 = 0; float b1 = p[0];
#pragma unroll
        for (int e = 1; e < NEXP; ++e) if (p[e] > b1) { b1 = p[e]; e1 = e; }
        int e2 = (e1 == 0) ? 1 : 0; float b2 = p[e2];
#pragma unroll
        for (int e = 0; e < NEXP; ++e)
            if (e != e1 && e != ((e1 == 0) ? 1 : 0) && p[e] > b2) { b2 = p[e]; e2 = e; }
        topk_idx[2 * t]     = e1;  topk_idx[2 * t + 1] = e2;
        topk_w[2 * t]       = b1;  topk_w[2 * t + 1]   = b2;
        ent_s[wv] = ent;
    }
    __syncthreads();
    if (threadIdx.x == 0)
        ent_partial[blockIdx.x] = ent_s[0] + ent_s[1] + ent_s[2] + ent_s[3];

    // ---- appended: expert_w fp32 -> bf16 (grid-stride, 16 iters) ----
    const int n8 = (NEXP * H_OUT * D_IN) / 8;        // 8.39M chunks
    int stride = gridDim.x * 256;
    for (int i = blockIdx.x * 256 + threadIdx.x; i < n8; i += stride) {
        const float4* p = (const float4*)expert_w + (size_t)i * 2;
        float4 a = p[0], b = p[1];
        bf16x8 v;
        v[0] = f2bf(a.x); v[1] = f2bf(a.y); v[2] = f2bf(a.z); v[3] = f2bf(a.w);
        v[4] = f2bf(b.x); v[5] = f2bf(b.y); v[6] = f2bf(b.z); v[7] = f2bf(b.w);
        *(bf16x8*)(wb + (size_t)i * 8) = v;
    }
}

// ---------------------------------------------------------------------------
// Kernel 2: scatter. LDS-binned, fixed per-expert regions.
// ---------------------------------------------------------------------------
__global__ __launch_bounds__(256) void scatter_kernel(
    const int* __restrict__ topk_idx, const float* __restrict__ topk_w,
    int* __restrict__ cursors, int* __restrict__ tok_list,
    float* __restrict__ w_list)
{
    __shared__ int lcnt[NEXP], lbase[NEXP];
    const int tid = threadIdx.x;
    const int t = blockIdx.x * 256 + tid;
    if (tid < NEXP) lcnt[tid] = 0;
    __syncthreads();
    int e0 = topk_idx[2 * t], e1 = topk_idx[2 * t + 1];
    float w0 = topk_w[2 * t], w1 = topk_w[2 * t + 1];
    int p0 = atomicAdd(&lcnt[e0], 1);
    int p1 = atomicAdd(&lcnt[e1], 1);
    __syncthreads();
    if (tid < NEXP) lbase[tid] = atomicAdd(&cursors[tid], lcnt[tid]);
    __syncthreads();
    int d0 = e0 * REGION + lbase[e0] + p0;
    int d1 = e1 * REGION + lbase[e1] + p1;
    tok_list[d0] = t;  w_list[d0] = w0;
    tok_list[d1] = t;  w_list[d1] = w1;
}

// ---------------------------------------------------------------------------
// Kernel 3: finalize — entropy reduce + overuse penalty (counts = cursors).
// Launched AFTER moe_gemm (off the critical path).
// ---------------------------------------------------------------------------
__global__ __launch_bounds__(256) void finalize_kernel(
    const int* __restrict__ counts, const float* __restrict__ ent_partial,
    float* __restrict__ loss_out)
{
    __shared__ float red[256];
    float s = 0.f;
    for (int i = threadIdx.x; i < N_TOK / 4; i += 256) s += ent_partial[i];
    red[threadIdx.x] = s;
    __syncthreads();
    for (int st = 128; st > 0; st >>= 1) {
        if (threadIdx.x < st) red[threadIdx.x] += red[threadIdx.x + st];
        __syncthreads();
    }
    if (threadIdx.x == 0) {
        float loss = ENT_W * red[0] / (float)N_TOK;
        for (int e = 0; e < NEXP; ++e) {
            float r = (float)counts[e] / (float)N_TOK - MAX_USAGE;
            if (r > 0.f) loss += r;
        }
        loss_out[0] = loss;
    }
}

// ---------------------------------------------------------------------------
// Kernel 4: grouped GEMM — r8's proven 128x128/BK=32 depth-2 counted pipeline
// (best measured: 532 us, MfmaUtil 22.6, 4 blocks/CU).
//   tile t: 8 ds_read (4 A + 4 B frags); lgkmcnt(0); s_barrier
//           stage tile t+2 (2A+2B gloads) into freed buf; 16 MFMA;
//           vmcnt(4) certifies tile t+1 (issued a full tile ago); s_barrier
// Swizzle: stage source slot (l&3)^((l>>3)&3), LDS dest linear; frag read
// slot kg^((row>>1)&3). Involution, 0 conflicts (measured).
// ---------------------------------------------------------------------------
__global__ __launch_bounds__(256, 4) void moe_gemm(
    const short* __restrict__ xb, const short* __restrict__ wb,
    const float* __restrict__ expert_b, const int* __restrict__ tok_list,
    const float* __restrict__ w_list, const int* __restrict__ counts,
    float* __restrict__ out)
{
    const int bid = blockIdx.x;
    const int e   = bid / (TM_MAX * TILES_H);
    const int rem = bid % (TM_MAX * TILES_H);
    const int tm  = rem / TILES_H;
    const int th  = rem % TILES_H;     // th inner: consecutive bids share A-tile

    const int cnt = counts[e];
    if (tm * TM >= cnt) return;
    const int valid = cnt - tm * TM;
    const int hbase = th * TH;

    __shared__ __align__(16) short A_s[2][BUFSZ];   // 2 x 8 KB
    __shared__ __align__(16) short B_s[2][BUFSZ];   // 2 x 8 KB
    __shared__ int   tok_s[TM];
    __shared__ float wgt_s[TM];

    const int tid = threadIdx.x;
    if (tid < TM) {
        bool v = tid < valid;
        int src = e * REGION + tm * TM + tid;
        tok_s[tid] = v ? tok_list[src] : 0;
        wgt_s[tid] = v ? w_list[src] : 0.f;
    }
    __syncthreads();

    const int lane = tid & 63;
    const int wv = tid >> 6;

    // staging: 8 x 1KB chunks per operand-tile; wave wv owns chunks wv*2+j.
    // chunk c covers rows c*16..c*16+15; lane l -> row c*16+(l>>2),
    // source slot (l&3)^((l>>3)&3) (involution; (row>>1)&3 == (l>>3)&3).
    const char* asrc[2];
    const char* bsrc[2];
    int dst_off[2];                    // shorts, wave-uniform (+lane*16B by HW)
#pragma unroll
    for (int j = 0; j < 2; ++j) {
        int c = wv * 2 + j;
        int r = c * 16 + (lane >> 2);
        int s2 = (lane & 3) ^ ((lane >> 3) & 3);
        asrc[j] = (const char*)(xb + (size_t)tok_s[r] * D_IN) + s2 * 16;
        bsrc[j] = (const char*)(wb + ((size_t)e * H_OUT + hbase + r) * D_IN) + s2 * 16;
        dst_off[j] = c * 512;
    }

    const int rr = lane & 15, kg = lane >> 4;
    const int wr = wv >> 1, wc = wv & 1;

    // fragment LDS offsets (shorts), swizzled to match staging involution
    int aoff[4], boff[4];
#pragma unroll
    for (int mi = 0; mi < 4; ++mi) {
        int row = wr * 64 + mi * 16 + rr;
        aoff[mi] = row * 32 + (kg ^ ((row >> 1) & 3)) * 8;
        int rowb = wc * 64 + mi * 16 + rr;
        boff[mi] = rowb * 32 + (kg ^ ((rowb >> 1) & 3)) * 8;
    }

    f32x4 acc[4][4] = {};

#define STAGE_KT(buf)                                                      \
    {                                                                      \
        short* Aso = (short*)A_s[buf];                                     \
        short* Bso = (short*)B_s[buf];                                     \
        gload16(asrc[0], Aso + dst_off[0]); asrc[0] += BK * 2;             \
        gload16(bsrc[0], Bso + dst_off[0]); bsrc[0] += BK * 2;             \
        gload16(asrc[1], Aso + dst_off[1]); asrc[1] += BK * 2;             \
        gload16(bsrc[1], Bso + dst_off[1]); bsrc[1] += BK * 2;             \
    }

    // prologue: stage K-tiles 0 (buf0) and 1 (buf1); certify tile 0 only.
    STAGE_KT(0);
    STAGE_KT(1);
    asm volatile("s_waitcnt vmcnt(4)" ::: "memory");   // tile 0 landed
    __builtin_amdgcn_sched_barrier(0);
    __builtin_amdgcn_s_barrier();

    for (int kt = 0; kt < NKT; ++kt) {
        const short* Ac = A_s[kt & 1];
        const short* Bc = B_s[kt & 1];

        // consume current tile entirely into registers
        bf16x8 af[4], bv[4];
#pragma unroll
        for (int mi = 0; mi < 4; ++mi) af[mi] = *(const bf16x8*)&Ac[aoff[mi]];
#pragma unroll
        for (int ni = 0; ni < 4; ++ni) bv[ni] = *(const bf16x8*)&Bc[boff[ni]];
        asm volatile("s_waitcnt lgkmcnt(0)" ::: "memory");
        __builtin_amdgcn_sched_barrier(0);
        __builtin_amdgcn_s_barrier();          // all waves done reading buf[kt&1]

        // stage tile kt+2 into the freed buffer (loads fly under MFMA)
        if (kt + 2 < NKT) STAGE_KT(kt & 1);

        __builtin_amdgcn_s_setprio(1);
#pragma unroll
        for (int mi = 0; mi < 4; ++mi)
#pragma unroll
            for (int ni = 0; ni < 4; ++ni)
                acc[mi][ni] = __builtin_amdgcn_mfma_f32_16x16x32_bf16(
                    af[mi], bv[ni], acc[mi][ni], 0, 0, 0);
        __builtin_amdgcn_s_setprio(0);

        // certify tile kt+1 (issued one full tile ago); deep prefetch stays.
        if (kt + 2 < NKT) {
            asm volatile("s_waitcnt vmcnt(4)" ::: "memory");
        } else if (kt + 1 < NKT) {
            asm volatile("s_waitcnt vmcnt(0)" ::: "memory");
        }
        __builtin_amdgcn_sched_barrier(0);
        __builtin_amdgcn_s_barrier();          // buf[(kt+1)&1] valid for all
    }
#undef STAGE_KT

    // epilogue: C/D layout col=lane&15, row=(lane>>4)*4+i
    const float* bias = expert_b + (size_t)e * H_OUT + hbase;
#pragma unroll
    for (int mi = 0; mi < 4; ++mi) {
#pragma unroll
        for (int ni = 0; ni < 4; ++ni) {
            int col = wc * 64 + ni * 16 + rr;
            float be = bias[col];
#pragma unroll
            for (int i = 0; i < 4; ++i) {
                int r = wr * 64 + mi * 16 + kg * 4 + i;
                if (r < valid) {
                    float val = wgt_s[r] * (acc[mi][ni][i] + be);
                    atomicAdd(&out[(size_t)tok_s[r] * H_OUT + hbase + col], val);
                }
            }
        }
    }
}

// ---------------------------------------------------------------------------
// Workspace layout (<= 162 MB):
//   0        topk_idx    64 KB
//   64K      topk_w      64 KB
//   128K     cursors     64 B
//   128K+256 ent_partial 8 KB
//   160K     tok_list    256 KB  (8 regions x 8192)
//   416K     w_list      256 KB
//   1M       xb  bf16    32 MB
//   34M      wb  bf16    128 MB  (row-major)
// ---------------------------------------------------------------------------
extern "C" void kernel_launch(void* const* d_in, const int* in_sizes, int n_in,
                              void* d_out, int out_size, void* d_ws, size_t ws_size,
                              hipStream_t stream) {
    const float* x        = (const float*)d_in[0];
    const float* gate_w   = (const float*)d_in[1];
    const float* gate_b   = (const float*)d_in[2];
    const float* expert_w = (const float*)d_in[3];
    const float* expert_b = (const float*)d_in[4];
    float* out = (float*)d_out;
    char* ws = (char*)d_ws;

    int*   topk_idx    = (int*)(ws);
    float* topk_w      = (float*)(ws + (64 << 10));
    int*   cursors     = (int*)(ws + (128 << 10));
    float* ent_partial = (float*)(ws + (128 << 10) + 256);
    int*   tok_list    = (int*)(ws + (160 << 10));
    float* w_list      = (float*)(ws + (416 << 10));
    short* xb          = (short*)(ws + (1ull << 20));
    short* wb          = (short*)(ws + (34ull << 20));

    hipMemsetAsync(cursors, 0, 64, stream);
    hipMemsetAsync(d_out, 0, (size_t)out_size * sizeof(float), stream);

    gate_cvt_kernel<<<N_TOK / 4, 256, 0, stream>>>(x, gate_w, gate_b, topk_idx,
                                                   topk_w, ent_partial, xb,
                                                   expert_w, wb);
    scatter_kernel<<<N_TOK / 256, 256, 0, stream>>>(topk_idx, topk_w, cursors,
                                                    tok_list, w_list);
    moe_gemm<<<NEXP * TM_MAX * TILES_H, 256, 0, stream>>>(
        xb, wb, expert_b, tok_list, w_list, cursors, out);
    finalize_kernel<<<1, 256, 0, stream>>>(cursors, ent_partial,
                                           out + (size_t)N_TOK * H_OUT);
}